// Round 4
// baseline (319.296 us; speedup 1.0000x reference)
//
#include <hip/hip_runtime.h>

#define NUM_LEVELS 16
#define LOG2_HASHMAP 19
#define TABLE_SIZE (1u << LOG2_HASHMAP)
#define PPT 8   // points per thread in the gather stage

typedef unsigned long long u64;   // opaque 8-byte carrier for float2 payloads

// ---------------- Stage 1: XCD-pinned gather, 8 points/thread --------------
// blockIdx.x % 8 == XCD (round-robin dispatch). XCD x does level x then x+8,
// so each XCD's 4 MB L2 holds exactly one level's 4 MB table at a time
// (round-3 counters confirmed: table duplication gone, FETCH 607->512 MB).
// Round-3 lesson: 1 gather/thread + 131K tiny blocks left the gather
// latency-bound. Here each thread handles 8 grid-strided points at one
// level: 24 coalesced xyz loads -> 8 hashes -> 8 INDEPENDENT table gathers
// in flight -> 8 coalesced non-temporal stores. 8x MLP, 8x fewer blocks.
//
// Hash math: w = (u32)(x*2^19) is exact (power-of-2 scale of f32), and
// ix_l = w >> (15-l) equals trunc(x*16*2^l) by the floor-nesting identity
// -> bit-identical to the reference's per-level f32 scale + int64 trunc.
// uint32 wraparound multiply preserves the low 19 bits of the int64 hash.
__global__ __launch_bounds__(256) void gather_kernel(
    const float* __restrict__ xyz,
    const float* __restrict__ tables,
    u64* __restrict__ ws,
    int n_points, int blocks_per_level, int stride_pts)
{
    int b     = blockIdx.x;
    int xcd   = b & 7;                 // XCD this block lands on
    int j     = b >> 3;                // sequence index within this XCD
    int phase = (j >= blocks_per_level) ? 1 : 0;
    int l     = xcd + (phase << 3);    // level pinned to this XCD
    int jj    = j - phase * blocks_per_level;
    int base  = jj * 256 + (int)threadIdx.x;

    const u64* tbl = (const u64*)tables + ((size_t)l << LOG2_HASHMAP);
    u64* wsl = ws + (size_t)l * n_points;
    int shift = 15 - l;

    unsigned hh[PPT];
    int      nn[PPT];
    bool     ok[PPT];
#pragma unroll
    for (int s = 0; s < PPT; ++s) {
        int n = base + s * stride_pts;     // grid-stride: coalesced every s
        nn[s] = n;
        ok[s] = (n < n_points);
        int ncl = ok[s] ? n : 0;           // masked lanes read point 0 (harmless)
        float x = xyz[ncl * 3 + 0];
        float y = xyz[ncl * 3 + 1];
        float z = xyz[ncl * 3 + 2];
        unsigned wx = (unsigned)(x * 524288.0f) >> shift;
        unsigned wy = (unsigned)(y * 524288.0f) >> shift;
        unsigned wz = (unsigned)(z * 524288.0f) >> shift;
        hh[s] = (wx ^ (wy * 2654435761u) ^ (wz * 805459861u)) & (TABLE_SIZE - 1u);
    }

    u64 f[PPT];
#pragma unroll
    for (int s = 0; s < PPT; ++s)          // 8 independent gathers in flight
        f[s] = tbl[hh[s]];

#pragma unroll
    for (int s = 0; s < PPT; ++s)
        if (ok[s])
            __builtin_nontemporal_store(f[s], wsl + nn[s]);
}

// ---------------- Stage 2: transpose ws[16][N] -> out[N][16] ----------------
// Measured 5.6 TB/s (near streaming ceiling) — unchanged.
__global__ __launch_bounds__(256) void transpose_kernel(
    const u64* __restrict__ ws,
    u64* __restrict__ out,
    int n_points)
{
    __shared__ u64 tile[128][NUM_LEVELS + 1];  // +1 pad: balanced banks both phases
    int n0 = blockIdx.x * 128;

    for (int i = threadIdx.x; i < 128 * NUM_LEVELS; i += 256) {
        int l = i >> 7;
        int n = i & 127;
        int gn = n0 + n;
        u64 v = (gn < n_points)
                  ? __builtin_nontemporal_load(ws + (size_t)l * n_points + gn)
                  : 0ull;
        tile[n][l] = v;
    }
    __syncthreads();

    for (int i = threadIdx.x; i < 128 * NUM_LEVELS; i += 256) {
        int n = i >> 4;
        int l = i & 15;
        if (n0 + n < n_points)
            __builtin_nontemporal_store(tile[n][l], out + (size_t)n0 * NUM_LEVELS + i);
    }
}

// ---------------- Fallback (round-1 kernel) if ws too small ----------------
__global__ __launch_bounds__(256) void fused_kernel(
    const float* __restrict__ xyz,
    const float* __restrict__ tables,
    u64* __restrict__ out,
    int n_points)
{
    int tid = blockIdx.x * blockDim.x + threadIdx.x;
    int n = tid >> 4;
    int l = tid & 15;
    if (n >= n_points) return;
    float x = xyz[n * 3 + 0], y = xyz[n * 3 + 1], z = xyz[n * 3 + 2];
    float res = (float)(16u << l);
    unsigned ix = (unsigned)(x * res);
    unsigned iy = (unsigned)(y * res);
    unsigned iz = (unsigned)(z * res);
    unsigned h = (ix ^ (iy * 2654435761u) ^ (iz * 805459861u)) & (TABLE_SIZE - 1u);
    u64 f = *((const u64*)tables + (((size_t)l << LOG2_HASHMAP) + h));
    out[(size_t)n * NUM_LEVELS + l] = f;
}

extern "C" void kernel_launch(void* const* d_in, const int* in_sizes, int n_in,
                              void* d_out, int out_size, void* d_ws, size_t ws_size,
                              hipStream_t stream) {
    const float* xyz    = (const float*)d_in[0];
    const float* tables = (const float*)d_in[1];

    int n_points = in_sizes[0] / 3;
    size_t ws_needed = (size_t)n_points * NUM_LEVELS * sizeof(u64);

    if (ws_size >= ws_needed) {
        int blocks_per_level = (n_points + 256 * PPT - 1) / (256 * PPT);
        int stride_pts = blocks_per_level * 256;
        int grid1 = blocks_per_level * NUM_LEVELS;   // divisible by 8
        gather_kernel<<<grid1, 256, 0, stream>>>(
            xyz, tables, (u64*)d_ws, n_points, blocks_per_level, stride_pts);

        int grid2 = (n_points + 127) / 128;
        transpose_kernel<<<grid2, 256, 0, stream>>>(
            (const u64*)d_ws, (u64*)d_out, n_points);
    } else {
        int total = n_points * NUM_LEVELS;
        int grid = (total + 255) / 256;
        fused_kernel<<<grid, 256, 0, stream>>>(xyz, tables, (u64*)d_out, n_points);
    }
}